// Round 4
// baseline (1252.509 us; speedup 1.0000x reference)
//
#include <hip/hip_runtime.h>
#include <cstdint>
#include <cstddef>

#define THREADS 256
#define ET 64

typedef __attribute__((ext_vector_type(8))) short short8;
typedef __attribute__((ext_vector_type(4))) float f32x4;

__device__ __forceinline__ float reluf(float v) { return fmaxf(v, 0.0f); }

__device__ __forceinline__ unsigned short f2bf(float f) {
    union { float f; unsigned u; } v; v.f = f;
    unsigned r = v.u + 0x7fff + ((v.u >> 16) & 1);   // RNE
    return (unsigned short)(r >> 16);
}
__device__ __forceinline__ unsigned pack2(float a, float b) {
    return (unsigned)f2bf(a) | ((unsigned)f2bf(b) << 16);
}
__device__ __forceinline__ float bf2f(unsigned short u) {
    return __uint_as_float((unsigned)u << 16);
}

// ---------------------------------------------------------------------------
// Prep: W23T[n][k] = sum_j ew2[k][j]*lew[j][n]  (bf16), c2[n] = eb2 @ lew
// ---------------------------------------------------------------------------
__global__ __launch_bounds__(128) void prep_kernel(
    const float* __restrict__ ew2, const float* __restrict__ eb2,
    const float* __restrict__ lew, unsigned short* __restrict__ w23t,
    float* __restrict__ c2)
{
    __shared__ float s_part[128];
    const int n = blockIdx.x;     // 0..255
    const int k = threadIdx.x;    // 0..127
    float acc = 0.0f;
#pragma unroll 4
    for (int j = 0; j < 128; ++j)
        acc = fmaf(ew2[k * 128 + j], lew[j * 256 + n], acc);
    w23t[n * 128 + k] = f2bf(acc);
    s_part[k] = eb2[k] * lew[k * 256 + n];
    __syncthreads();
    if (k == 0) {
        float s = 0.0f;
        for (int j = 0; j < 128; ++j) s += s_part[j];
        c2[n] = s;
    }
}

// w1t[n][k] = bf16(w1[k][n]); w2t likewise. 512 blocks x 256 threads.
__global__ __launch_bounds__(256) void prep_wt_kernel(
    const float* __restrict__ w1, const float* __restrict__ w2,
    unsigned short* __restrict__ w1t, unsigned short* __restrict__ w2t)
{
    const int bi = blockIdx.x;
    const float* src = (bi < 256) ? w1 : w2;
    unsigned short* dst = (bi < 256) ? w1t : w2t;
    const int k = bi & 255;
    const int n = threadIdx.x;
    dst[n * 256 + k] = f2bf(src[k * 256 + n]);
}

// xb = bf16(x), 8 elems/thread
__global__ __launch_bounds__(256) void xcast_kernel(
    const float* __restrict__ x, unsigned short* __restrict__ xb)
{
    const size_t i = ((size_t)blockIdx.x * 256 + threadIdx.x) * 8;
    float4 v0 = *(const float4*)(x + i);
    float4 v1 = *(const float4*)(x + i + 4);
    uint4 pk;
    pk.x = pack2(v0.x, v0.y); pk.y = pack2(v0.z, v0.w);
    pk.z = pack2(v1.x, v1.y); pk.w = pack2(v1.z, v1.w);
    *(uint4*)(xb + i) = pk;
}

// ---------------------------------------------------------------------------
// Counting sort of edges by dst: hist -> exclusive scan -> scatter(perm)
// ---------------------------------------------------------------------------
__global__ __launch_bounds__(256) void hist_kernel(
    const int* __restrict__ ei, int* __restrict__ counts, int E)
{
    int e = blockIdx.x * 256 + threadIdx.x;
    if (e < E) atomicAdd(&counts[ei[(long long)E + e]], 1);
}

__global__ __launch_bounds__(1024) void scan_kernel(int* __restrict__ counts, int N)
{
    __shared__ int wsum[16];
    __shared__ int carry;
    const int tid = threadIdx.x;
    const int lane = tid & 63, wid = tid >> 6;
    if (tid == 0) carry = 0;
    __syncthreads();
    for (int chunk = 0; chunk < N; chunk += 1024) {
        int idx = chunk + tid;
        int v = (idx < N) ? counts[idx] : 0;
        int incl = v;
#pragma unroll
        for (int off = 1; off < 64; off <<= 1) {
            int t = __shfl_up(incl, off);
            if (lane >= off) incl += t;
        }
        if (lane == 63) wsum[wid] = incl;
        __syncthreads();
        int wpre = 0, tot = 0;
#pragma unroll
        for (int w = 0; w < 16; ++w) {
            int s = wsum[w];
            tot += s;
            if (w < wid) wpre += s;
        }
        int b = carry;
        if (idx < N) counts[idx] = b + wpre + incl - v;
        __syncthreads();
        if (tid == 0) carry = b + tot;
        __syncthreads();
    }
}

__global__ __launch_bounds__(256) void scatter_kernel(
    const int* __restrict__ ei, int* __restrict__ cursor,
    int* __restrict__ perm, int E)
{
    int e = blockIdx.x * 256 + threadIdx.x;
    if (e < E) {
        int d = ei[(long long)E + e];
        int pos = atomicAdd(&cursor[d], 1);
        perm[pos] = e;
    }
}

// ---------------------------------------------------------------------------
// Edge pipeline (dst-sorted, MFMA). Block = 64 edges, 4 waves.
// x rows staged to LDS (bf16, coalesced, issued early); epilogue reads LDS.
// ---------------------------------------------------------------------------
__global__ __launch_bounds__(THREADS, 2) void edge_mfma_kernel(
    const unsigned short* __restrict__ xb, const int* __restrict__ ei,
    const float* __restrict__ ea,
    const float* __restrict__ ew1, const float* __restrict__ eb1,
    const unsigned short* __restrict__ w23t, const float* __restrict__ c2,
    const float* __restrict__ leb, const int* __restrict__ perm,
    float* __restrict__ aggr, int E)
{
    __shared__ float s_attr[ET * 17];
    __shared__ uint4 s_hid4[64 * 16];          // 64 rows x 256B, granule ^= row&15
    __shared__ unsigned short s_x[64 * 264];   // x rows bf16, stride 264
    __shared__ int   s_pe[ET];
    __shared__ int   s_src[ET];
    __shared__ int   s_dst[ET];
    __shared__ float s_pol[ET];

    const int tid = threadIdx.x;
    const long long eb0 = (long long)blockIdx.x * ET;

    if (tid < ET) {
        int e = perm[eb0 + tid];
        s_pe[tid]  = e;
        s_src[tid] = ei[e];
        s_dst[tid] = ei[(long long)E + e];
    }
    __syncthreads();

    // ---- issue x-row loads early (latency hides under attr load + phase1)
    const int xrow = tid >> 2;   // 0..63
    const int xseg = tid & 3;    // 64 shorts each
    uint4 xv[8];
    {
        const uint4* xp = (const uint4*)(xb + (size_t)s_src[xrow] * 256) + xseg * 8;
#pragma unroll
        for (int j = 0; j < 8; ++j) xv[j] = xp[j];
    }

    for (int i = tid; i < ET * 17; i += THREADS) {
        int idx = i / 17;
        int k = i - idx * 17;
        s_attr[i] = ea[(size_t)s_pe[idx] * 17 + k];
    }
    __syncthreads();
    if (tid < ET) s_pol[tid] = fminf(fmaxf(s_attr[tid * 17], 0.0f), 1.0f) + 0.01f;

    const int el = tid & 63;
    const int c  = tid >> 6;

    // ---- phase 1: hid = relu(raw @ ew1 + eb1); thread does dims 32c..32c+31
    float acc1[32];
#pragma unroll
    for (int j4 = 0; j4 < 8; ++j4) {
        float4 b = *(const float4*)(eb1 + c * 32 + j4 * 4);
        acc1[j4*4+0] = b.x; acc1[j4*4+1] = b.y;
        acc1[j4*4+2] = b.z; acc1[j4*4+3] = b.w;
    }
#pragma unroll
    for (int k = 0; k < 16; ++k) {
        float rk = s_attr[el * 17 + 1 + k];
#pragma unroll
        for (int j4 = 0; j4 < 8; ++j4) {
            float4 wv = *(const float4*)(ew1 + k * 128 + c * 32 + j4 * 4);
            acc1[j4*4+0] = fmaf(rk, wv.x, acc1[j4*4+0]);
            acc1[j4*4+1] = fmaf(rk, wv.y, acc1[j4*4+1]);
            acc1[j4*4+2] = fmaf(rk, wv.z, acc1[j4*4+2]);
            acc1[j4*4+3] = fmaf(rk, wv.w, acc1[j4*4+3]);
        }
    }
    // relu -> bf16 pack -> swizzled LDS write (granule ^= row&15)
#pragma unroll
    for (int q = 0; q < 4; ++q) {
        uint4 pk;
        pk.x = pack2(reluf(acc1[q*8+0]), reluf(acc1[q*8+1]));
        pk.y = pack2(reluf(acc1[q*8+2]), reluf(acc1[q*8+3]));
        pk.z = pack2(reluf(acc1[q*8+4]), reluf(acc1[q*8+5]));
        pk.w = pack2(reluf(acc1[q*8+6]), reluf(acc1[q*8+7]));
        s_hid4[el * 16 + ((4 * c + q) ^ (el & 15))] = pk;
    }
    // ---- stage x tile into LDS (bf16, stride 264 shorts)
    {
        unsigned short* xd = &s_x[xrow * 264 + xseg * 64];
#pragma unroll
        for (int j = 0; j < 8; ++j) *(uint4*)(xd + j * 8) = xv[j];
    }
    __syncthreads();

    // ---- MFMA: wave w -> edge rows 16w..16w+15, all 256 output dims ----
    const int lane = el;
    const int w = c;
    short8 afr[4];
#pragma unroll
    for (int kt = 0; kt < 4; ++kt) {
        int row = 16 * w + (lane & 15);
        afr[kt] = *(const short8*)&s_hid4[row * 16 + ((4 * kt + (lane >> 4)) ^ (lane & 15))];
    }
    const short8* wb = (const short8*)w23t;   // row n = 16 short8 chunks
    f32x4 acc[16];
#pragma unroll
    for (int nt = 0; nt < 16; ++nt) acc[nt] = (f32x4){0.f, 0.f, 0.f, 0.f};
#pragma unroll
    for (int kt = 0; kt < 4; ++kt) {
#pragma unroll
        for (int nt = 0; nt < 16; ++nt) {
            short8 b = wb[(nt * 16 + (lane & 15)) * 16 + 4 * kt + (lane >> 4)];
            acc[nt] = __builtin_amdgcn_mfma_f32_16x16x32_bf16(afr[kt], b, acc[nt], 0, 0, 0);
        }
    }

    // ---- epilogue: C-layout row m = 4*(lane>>4)+r, col n = 16*nt+(lane&15)
    const int g4 = lane >> 4, nl = lane & 15;
    int   d_[4];
    float p_[4];
#pragma unroll
    for (int r = 0; r < 4; ++r) {
        int erow = 16 * w + 4 * g4 + r;
        d_[r] = s_dst[erow]; p_[r] = s_pol[erow];
    }
    float c2v[16], lbv[16];
#pragma unroll
    for (int nt = 0; nt < 16; ++nt) {
        c2v[nt] = c2[nt * 16 + nl];
        lbv[nt] = leb[nt * 16 + nl];
    }
#pragma unroll
    for (int r = 0; r < 4; ++r) {
        const unsigned short* xs = &s_x[(16 * w + 4 * g4 + r) * 264 + nl];
#pragma unroll
        for (int nt = 0; nt < 16; ++nt) {
            float m = fmaf(p_[r], acc[nt][r] + c2v[nt], lbv[nt]) + bf2f(xs[nt * 16]);
            acc[nt][r] = fmaxf(m, 0.0f);
        }
    }

    // ---- segmented reduce: in-lane suffix over r (4 consecutive edges) ----
#pragma unroll
    for (int r = 2; r >= 0; --r) {
        bool mm = (d_[r] == d_[r + 1]);
#pragma unroll
        for (int nt = 0; nt < 16; ++nt)
            if (mm) acc[nt][r] += acc[nt][r + 1];
    }
    // cross-group (16-lane quads) continuation: E = run-sum beyond my quad
    int d0n   = __shfl_down(d_[0], 16);
    int fulln = __shfl_down((int)(d_[0] == d_[3]), 16);
    bool cont = (g4 < 3) && (d_[3] == d0n);
    float Cn[16], Ev[16];
#pragma unroll
    for (int nt = 0; nt < 16; ++nt) {
        Cn[nt] = __shfl_down(acc[nt][0], 16);
        Ev[nt] = 0.0f;
    }
    for (int it = 0; it < 3; ++it) {
#pragma unroll
        for (int nt = 0; nt < 16; ++nt) {
            float En = __shfl_down(Ev[nt], 16);
            Ev[nt] = cont ? (Cn[nt] + (fulln ? En : 0.0f)) : 0.0f;
        }
    }
#pragma unroll
    for (int r = 0; r < 4; ++r) {
        bool tail = (d_[r] == d_[3]);
#pragma unroll
        for (int nt = 0; nt < 16; ++nt)
            if (tail) acc[nt][r] += Ev[nt];
    }
    // leaders write
    int dpl = __shfl_up(d_[3], 16);
    bool lead0 = (g4 == 0) || (d_[0] != dpl);
#pragma unroll
    for (int r = 0; r < 4; ++r) {
        bool ld = (r == 0) ? lead0 : (d_[r] != d_[r - 1]);
        if (ld) {
            float* ap = aggr + (size_t)d_[r] * 256 + nl;
#pragma unroll
            for (int nt = 0; nt < 16; ++nt)
                unsafeAtomicAdd(ap + nt * 16, acc[nt][r]);
        }
    }
}

// ---------------------------------------------------------------------------
// node1: h = x + aggr -> bf16 -> MFMA @ w1t -> +b1 -> LN -> *g+b -> relu
//        -> bf16 -> hb (global). 64 rows/block, 4 waves.
// ---------------------------------------------------------------------------
__global__ __launch_bounds__(THREADS, 2) void node1_kernel(
    const float* __restrict__ x, const float* __restrict__ aggr,
    const unsigned short* __restrict__ w1t, const float* __restrict__ b1,
    const float* __restrict__ lng, const float* __restrict__ lnb,
    unsigned short* __restrict__ hb, int N)
{
    __shared__ uint4 s_h[64 * 32];   // 64 rows x 512B bf16, granule ^= row&15

    const int tid = threadIdx.x;
    const int nb = blockIdx.x * 64;
    const int el = tid & 63;
    const int c  = tid >> 6;

    // phase A: h = x + aggr -> bf16 swizzled LDS (thread: row el, dims 64c..)
    {
        int row = nb + el; if (row >= N) row = N - 1;
        const float4* xp = (const float4*)(x + (size_t)row * 256 + c * 64);
        const float4* ap = (const float4*)(aggr + (size_t)row * 256 + c * 64);
#pragma unroll
        for (int q = 0; q < 8; ++q) {
            float4 v0 = xp[q*2], v1 = xp[q*2+1];
            float4 a0 = ap[q*2], a1 = ap[q*2+1];
            uint4 pk;
            pk.x = pack2(v0.x + a0.x, v0.y + a0.y);
            pk.y = pack2(v0.z + a0.z, v0.w + a0.w);
            pk.z = pack2(v1.x + a1.x, v1.y + a1.y);
            pk.w = pack2(v1.z + a1.z, v1.w + a1.w);
            s_h[el * 32 + ((c * 8 + q) ^ (el & 15))] = pk;
        }
    }
    __syncthreads();

    const int lane = el, w = c;
    const int nl = lane & 15, g4 = lane >> 4;
    const int arow = 16 * w + nl;

    short8 afr[8];
#pragma unroll
    for (int kt = 0; kt < 8; ++kt)
        afr[kt] = *(const short8*)&s_h[arow * 32 + ((kt * 4 + g4) ^ nl)];

    const short8* wb = (const short8*)w1t;   // [n][k]: 32 chunks/row
    f32x4 acc[16];
#pragma unroll
    for (int nt = 0; nt < 16; ++nt) acc[nt] = (f32x4){0.f, 0.f, 0.f, 0.f};
#pragma unroll
    for (int kt = 0; kt < 8; ++kt) {
#pragma unroll
        for (int nt = 0; nt < 16; ++nt) {
            short8 b = wb[(nt * 16 + nl) * 32 + kt * 4 + g4];
            acc[nt] = __builtin_amdgcn_mfma_f32_16x16x32_bf16(afr[kt], b, acc[nt], 0, 0, 0);
        }
    }

    // bias + LN + scale/shift + relu (rows 16w+4g4+r, cols nl+16nt)
    float b1v[16], gv[16], bv[16];
#pragma unroll
    for (int nt = 0; nt < 16; ++nt) {
        b1v[nt] = b1[nt * 16 + nl];
        gv[nt]  = lng[nt * 16 + nl];
        bv[nt]  = lnb[nt * 16 + nl];
    }
    unsigned short* sh = (unsigned short*)s_h;
#pragma unroll
    for (int r = 0; r < 4; ++r) {
        float s = 0.f, s2 = 0.f;
#pragma unroll
        for (int nt = 0; nt < 16; ++nt) {
            float v = acc[nt][r] + b1v[nt];
            acc[nt][r] = v;
            s += v; s2 = fmaf(v, v, s2);
        }
#pragma unroll
        for (int o = 1; o < 16; o <<= 1) {
            s  += __shfl_xor(s, o);
            s2 += __shfl_xor(s2, o);
        }
        float mu = s * (1.0f / 256.0f);
        float var = s2 * (1.0f / 256.0f) - mu * mu;
        float rs = rsqrtf(var + 1e-5f);
        int row = 16 * w + 4 * g4 + r;
#pragma unroll
        for (int nt = 0; nt < 16; ++nt) {
            float v = reluf(fmaf((acc[nt][r] - mu) * rs, gv[nt], bv[nt]));
            int d = nl + 16 * nt;
            // wave-local rows: safe to overwrite (only this wave reads them)
            sh[row * 256 + (((d >> 3) ^ (row & 15)) << 3) + (d & 7)] = f2bf(v);
        }
    }
    __syncthreads();

    // coalesced readout -> hb
    if (nb + el < N) {
        uint4* hp = (uint4*)(hb + (size_t)(nb + el) * 256 + c * 64);
#pragma unroll
        for (int q = 0; q < 8; ++q)
            hp[q] = s_h[el * 32 + ((c * 8 + q) ^ (el & 15))];
    }
}

// ---------------------------------------------------------------------------
// node2: out = hb @ w2t^T + b2 (fp32 out). A-frags straight from global.
// ---------------------------------------------------------------------------
__global__ __launch_bounds__(THREADS, 2) void node2_kernel(
    const unsigned short* __restrict__ hb, const unsigned short* __restrict__ w2t,
    const float* __restrict__ b2, float* __restrict__ out, int N)
{
    __shared__ float s_o[64 * 260];   // fp32 bounce, stride 260

    const int tid = threadIdx.x;
    const int nb = blockIdx.x * 64;
    const int el = tid & 63;
    const int c  = tid >> 6;
    const int lane = el, w = c;
    const int nl = lane & 15, g4 = lane >> 4;

    int arow = nb + 16 * w + nl; if (arow >= N) arow = N - 1;
    const short8* ap = (const short8*)(hb + (size_t)arow * 256);
    short8 afr[8];
#pragma unroll
    for (int kt = 0; kt < 8; ++kt) afr[kt] = ap[kt * 4 + g4];

    const short8* wb = (const short8*)w2t;
    f32x4 acc[16];
#pragma unroll
    for (int nt = 0; nt < 16; ++nt) acc[nt] = (f32x4){0.f, 0.f, 0.f, 0.f};
#pragma unroll
    for (int kt = 0; kt < 8; ++kt) {
#pragma unroll
        for (int nt = 0; nt < 16; ++nt) {
            short8 b = wb[(nt * 16 + nl) * 32 + kt * 4 + g4];
            acc[nt] = __builtin_amdgcn_mfma_f32_16x16x32_bf16(afr[kt], b, acc[nt], 0, 0, 0);
        }
    }

    float b2v[16];
#pragma unroll
    for (int nt = 0; nt < 16; ++nt) b2v[nt] = b2[nt * 16 + nl];
#pragma unroll
    for (int r = 0; r < 4; ++r) {
        int row = 16 * w + 4 * g4 + r;
#pragma unroll
        for (int nt = 0; nt < 16; ++nt)
            s_o[row * 260 + nl + 16 * nt] = acc[nt][r] + b2v[nt];
    }
    __syncthreads();

    if (nb + el < N) {
        float4* op = (float4*)(out + (size_t)(nb + el) * 256 + c * 64);
#pragma unroll
        for (int q = 0; q < 16; ++q)
            op[q] = *(float4*)&s_o[el * 260 + c * 64 + q * 4];
    }
}

extern "C" void kernel_launch(void* const* d_in, const int* in_sizes, int n_in,
                              void* d_out, int out_size, void* d_ws, size_t ws_size,
                              hipStream_t stream) {
    const float* x   = (const float*)d_in[0];
    const int*   ei  = (const int*)d_in[1];
    const float* ea  = (const float*)d_in[2];
    const float* ew1 = (const float*)d_in[3];
    const float* eb1 = (const float*)d_in[4];
    const float* ew2 = (const float*)d_in[5];
    const float* eb2 = (const float*)d_in[6];
    const float* lew = (const float*)d_in[7];
    const float* leb = (const float*)d_in[8];
    const float* w1  = (const float*)d_in[9];
    const float* b1  = (const float*)d_in[10];
    const float* lng = (const float*)d_in[11];
    const float* lnb = (const float*)d_in[12];
    const float* w2  = (const float*)d_in[13];
    const float* b2  = (const float*)d_in[14];
    float* out = (float*)d_out;

    const int N = in_sizes[0] / 256;
    const int E = in_sizes[1] / 2;

    float* aggr = (float*)d_ws;                           // N*256 f32
    char* p = (char*)(aggr + (size_t)N * 256);
    int* perm = (int*)p;                p += sizeof(int) * (size_t)E;
    int* counts = (int*)p;              p += sizeof(int) * (size_t)N;
    unsigned short* w23t = (unsigned short*)p;  p += 2 * 256 * 128;
    float* c2 = (float*)p;              p += 4 * 256;
    unsigned short* w1t = (unsigned short*)p;   p += 2 * 256 * 256;
    unsigned short* w2t = (unsigned short*)p;   p += 2 * 256 * 256;
    unsigned short* xb = (unsigned short*)p;    // N*256 bf16
    unsigned short* hb = xb;  // alias: xb consumed by edge before node1 writes

    hipMemsetAsync(aggr, 0, (size_t)N * 256 * sizeof(float), stream);
    hipMemsetAsync(counts, 0, (size_t)N * sizeof(int), stream);

    prep_kernel<<<256, 128, 0, stream>>>(ew2, eb2, lew, w23t, c2);
    prep_wt_kernel<<<512, 256, 0, stream>>>(w1, w2, w1t, w2t);
    xcast_kernel<<<(int)(((size_t)N * 256) / 2048), 256, 0, stream>>>(x, xb);

    hist_kernel<<<(E + 255) / 256, 256, 0, stream>>>(ei, counts, E);
    scan_kernel<<<1, 1024, 0, stream>>>(counts, N);
    scatter_kernel<<<(E + 255) / 256, 256, 0, stream>>>(ei, counts, perm, E);

    edge_mfma_kernel<<<E / ET, THREADS, 0, stream>>>(
        xb, ei, ea, ew1, eb1, w23t, c2, leb, perm, aggr, E);

    const int gb = (N + 63) / 64;
    node1_kernel<<<gb, THREADS, 0, stream>>>(x, aggr, w1t, b1, lng, lnb, hb, N);
    node2_kernel<<<gb, THREADS, 0, stream>>>(hb, w2t, b2, out, N);
}

// Round 5
// 897.562 us; speedup vs baseline: 1.3955x; 1.3955x over previous
//
#include <hip/hip_runtime.h>
#include <cstdint>
#include <cstddef>

#define THREADS 256
#define ET 64

typedef __attribute__((ext_vector_type(8))) short short8;
typedef __attribute__((ext_vector_type(4))) float f32x4;

__device__ __forceinline__ float reluf(float v) { return fmaxf(v, 0.0f); }

__device__ __forceinline__ unsigned short f2bf(float f) {
    union { float f; unsigned u; } v; v.f = f;
    unsigned r = v.u + 0x7fff + ((v.u >> 16) & 1);   // RNE
    return (unsigned short)(r >> 16);
}
__device__ __forceinline__ unsigned pack2(float a, float b) {
    return (unsigned)f2bf(a) | ((unsigned)f2bf(b) << 16);
}
__device__ __forceinline__ float bf2f(unsigned short u) {
    return __uint_as_float((unsigned)u << 16);
}
__device__ __forceinline__ void gload_lds16(const void* g, void* l) {
    __builtin_amdgcn_global_load_lds(
        (const __attribute__((address_space(1))) unsigned int*)g,
        (__attribute__((address_space(3))) unsigned int*)l, 16, 0, 0);
}

// ---------------------------------------------------------------------------
// Prep: W23T[n][k] = sum_j ew2[k][j]*lew[j][n]  (bf16), c2[n] = eb2 @ lew
// ---------------------------------------------------------------------------
__global__ __launch_bounds__(128) void prep_kernel(
    const float* __restrict__ ew2, const float* __restrict__ eb2,
    const float* __restrict__ lew, unsigned short* __restrict__ w23t,
    float* __restrict__ c2)
{
    __shared__ float s_part[128];
    const int n = blockIdx.x;     // 0..255
    const int k = threadIdx.x;    // 0..127
    float acc = 0.0f;
#pragma unroll 4
    for (int j = 0; j < 128; ++j)
        acc = fmaf(ew2[k * 128 + j], lew[j * 256 + n], acc);
    w23t[n * 128 + k] = f2bf(acc);
    s_part[k] = eb2[k] * lew[k * 256 + n];
    __syncthreads();
    if (k == 0) {
        float s = 0.0f;
        for (int j = 0; j < 128; ++j) s += s_part[j];
        c2[n] = s;
    }
}

// w1t[n][k] = bf16(w1[k][n]); w2t likewise. 512 blocks x 256 threads.
__global__ __launch_bounds__(256) void prep_wt_kernel(
    const float* __restrict__ w1, const float* __restrict__ w2,
    unsigned short* __restrict__ w1t, unsigned short* __restrict__ w2t)
{
    const int bi = blockIdx.x;
    const float* src = (bi < 256) ? w1 : w2;
    unsigned short* dst = (bi < 256) ? w1t : w2t;
    const int k = bi & 255;
    const int n = threadIdx.x;
    dst[n * 256 + k] = f2bf(src[k * 256 + n]);
}

// xb = bf16(x), 8 elems/thread
__global__ __launch_bounds__(256) void xcast_kernel(
    const float* __restrict__ x, unsigned short* __restrict__ xb)
{
    const size_t i = ((size_t)blockIdx.x * 256 + threadIdx.x) * 8;
    float4 v0 = *(const float4*)(x + i);
    float4 v1 = *(const float4*)(x + i + 4);
    uint4 pk;
    pk.x = pack2(v0.x, v0.y); pk.y = pack2(v0.z, v0.w);
    pk.z = pack2(v1.x, v1.y); pk.w = pack2(v1.z, v1.w);
    *(uint4*)(xb + i) = pk;
}

// ---------------------------------------------------------------------------
// Counting sort of edges by dst: hist -> 3-phase scan -> scatter(perm)
// ---------------------------------------------------------------------------
__global__ __launch_bounds__(256) void hist_kernel(
    const int* __restrict__ ei, int* __restrict__ counts, int E)
{
    int e = blockIdx.x * 256 + threadIdx.x;
    if (e < E) atomicAdd(&counts[ei[(long long)E + e]], 1);
}

__global__ __launch_bounds__(1024) void scan_a_kernel(
    int* __restrict__ counts, int* __restrict__ bsum, int N)
{
    __shared__ int wsum[16];
    const int tid = threadIdx.x;
    const int lane = tid & 63, wid = tid >> 6;
    const int idx = blockIdx.x * 1024 + tid;
    int v = (idx < N) ? counts[idx] : 0;
    int incl = v;
#pragma unroll
    for (int off = 1; off < 64; off <<= 1) {
        int t = __shfl_up(incl, off);
        if (lane >= off) incl += t;
    }
    if (lane == 63) wsum[wid] = incl;
    __syncthreads();
    int wpre = 0, tot = 0;
#pragma unroll
    for (int w = 0; w < 16; ++w) {
        int s = wsum[w];
        tot += s;
        if (w < wid) wpre += s;
    }
    if (idx < N) counts[idx] = wpre + incl - v;   // block-local exclusive
    if (tid == 0) bsum[blockIdx.x] = tot;
}

__global__ __launch_bounds__(64) void scan_b_kernel(int* __restrict__ bsum, int nb)
{
    const int lane = threadIdx.x;
    int v = (lane < nb) ? bsum[lane] : 0;
    int incl = v;
#pragma unroll
    for (int off = 1; off < 64; off <<= 1) {
        int t = __shfl_up(incl, off);
        if (lane >= off) incl += t;
    }
    if (lane < nb) bsum[lane] = incl - v;   // exclusive
}

__global__ __launch_bounds__(1024) void scan_c_kernel(
    int* __restrict__ counts, const int* __restrict__ bsum, int N)
{
    const int idx = blockIdx.x * 1024 + threadIdx.x;
    if (idx < N) counts[idx] += bsum[blockIdx.x];
}

__global__ __launch_bounds__(256) void scatter_kernel(
    const int* __restrict__ ei, int* __restrict__ cursor,
    int* __restrict__ perm, int E)
{
    int e = blockIdx.x * 256 + threadIdx.x;
    if (e < E) {
        int d = ei[(long long)E + e];
        int pos = atomicAdd(&cursor[d], 1);
        perm[pos] = e;
    }
}

// ---------------------------------------------------------------------------
// Edge pipeline (dst-sorted, MFMA). Block = 64 edges, 4 waves.
// W23T staged per block into LDS in two 32KB column-halves via
// global_load_lds (linear dest, XOR-swizzled SOURCE index so the b128
// B-frag reads spread uniformly across bank groups). x read directly from
// global bf16 in the epilogue (no VGPR staging -> no spill).
// ---------------------------------------------------------------------------
__global__ __launch_bounds__(THREADS, 3) void edge_mfma_kernel(
    const unsigned short* __restrict__ xb, const int* __restrict__ ei,
    const float* __restrict__ ea,
    const float* __restrict__ ew1, const float* __restrict__ eb1,
    const unsigned short* __restrict__ w23t, const float* __restrict__ c2,
    const float* __restrict__ leb, const int* __restrict__ perm,
    float* __restrict__ aggr, int E)
{
    __shared__ float s_attr[ET * 17];   //  4352 B
    __shared__ uint4 s_hid4[64 * 16];   // 16384 B, granule ^= row&15
    __shared__ uint4 s_w[2048];         // 32768 B, one column-half of W23T
    __shared__ int   s_pe[ET];
    __shared__ int   s_src[ET];
    __shared__ int   s_dst[ET];
    __shared__ float s_pol[ET];

    const int tid = threadIdx.x;
    const long long eb0 = (long long)blockIdx.x * ET;

    if (tid < ET) {
        int e = perm[eb0 + tid];
        s_pe[tid]  = e;
        s_src[tid] = ei[e];
        s_dst[tid] = ei[(long long)E + e];
    }
    // stage W23T half 0 (cols n=0..127, 32KB contiguous) -> s_w
    {
        int j = tid;            // granule index walked in 8 rounds
#pragma unroll
        for (int rnd = 0; rnd < 8; ++rnd, j += 256) {
            int fj = j ^ ((j >> 4) & 7);
            gload_lds16(w23t + (size_t)fj * 8, &s_w[j]);
        }
    }
    __syncthreads();
    for (int i = tid; i < ET * 17; i += THREADS) {
        int idx = i / 17;
        int k = i - idx * 17;
        s_attr[i] = ea[(size_t)s_pe[idx] * 17 + k];
    }
    __syncthreads();
    if (tid < ET) s_pol[tid] = fminf(fmaxf(s_attr[tid * 17], 0.0f), 1.0f) + 0.01f;

    const int el = tid & 63;
    const int c  = tid >> 6;

    // ---- phase 1: hid = relu(raw @ ew1 + eb1); thread does dims 32c..32c+31
    float acc1[32];
#pragma unroll
    for (int j4 = 0; j4 < 8; ++j4) {
        float4 b = *(const float4*)(eb1 + c * 32 + j4 * 4);
        acc1[j4*4+0] = b.x; acc1[j4*4+1] = b.y;
        acc1[j4*4+2] = b.z; acc1[j4*4+3] = b.w;
    }
#pragma unroll
    for (int k = 0; k < 16; ++k) {
        float rk = s_attr[el * 17 + 1 + k];
#pragma unroll
        for (int j4 = 0; j4 < 8; ++j4) {
            float4 wv = *(const float4*)(ew1 + k * 128 + c * 32 + j4 * 4);
            acc1[j4*4+0] = fmaf(rk, wv.x, acc1[j4*4+0]);
            acc1[j4*4+1] = fmaf(rk, wv.y, acc1[j4*4+1]);
            acc1[j4*4+2] = fmaf(rk, wv.z, acc1[j4*4+2]);
            acc1[j4*4+3] = fmaf(rk, wv.w, acc1[j4*4+3]);
        }
    }
    // relu -> bf16 pack -> swizzled LDS write (granule ^= row&15)
#pragma unroll
    for (int q = 0; q < 4; ++q) {
        uint4 pk;
        pk.x = pack2(reluf(acc1[q*8+0]), reluf(acc1[q*8+1]));
        pk.y = pack2(reluf(acc1[q*8+2]), reluf(acc1[q*8+3]));
        pk.z = pack2(reluf(acc1[q*8+4]), reluf(acc1[q*8+5]));
        pk.w = pack2(reluf(acc1[q*8+6]), reluf(acc1[q*8+7]));
        s_hid4[el * 16 + ((4 * c + q) ^ (el & 15))] = pk;
    }
    __syncthreads();   // drains vmcnt(0): W-half-0 staged; s_hid visible

    // ---- MFMA: wave w -> edge rows 16w..16w+15, all 256 output dims ----
    const int lane = el;
    const int w = c;
    const int nl = lane & 15, g4 = lane >> 4;

    short8 afr[4];
#pragma unroll
    for (int kt = 0; kt < 4; ++kt)
        afr[kt] = *(const short8*)&s_hid4[(16 * w + nl) * 16 + ((4 * kt + g4) ^ nl)];

    f32x4 acc[16];
#pragma unroll
    for (int nt = 0; nt < 16; ++nt) acc[nt] = (f32x4){0.f, 0.f, 0.f, 0.f};

#pragma unroll
    for (int h = 0; h < 2; ++h) {
        if (h) {
            __syncthreads();   // all waves done reading half 0
            const unsigned short* wh = w23t + 128 * 128;
            int j = tid;
#pragma unroll
            for (int rnd = 0; rnd < 8; ++rnd, j += 256) {
                int fj = j ^ ((j >> 4) & 7);
                gload_lds16(wh + (size_t)fj * 8, &s_w[j]);
            }
            __syncthreads();   // half 1 staged (barrier drains vmcnt)
        }
#pragma unroll
        for (int kt = 0; kt < 4; ++kt) {
#pragma unroll
            for (int ntl = 0; ntl < 8; ++ntl) {
                int cidx = (((ntl * 16 + nl) * 16 + kt * 4 + g4)) ^ (nl & 7);
                short8 b = *(const short8*)&s_w[cidx];
                acc[h * 8 + ntl] =
                    __builtin_amdgcn_mfma_f32_16x16x32_bf16(afr[kt], b, acc[h * 8 + ntl], 0, 0, 0);
            }
        }
    }

    // ---- epilogue: C-layout row m = 4*g4+r, col n = 16*nt+nl
    int   d_[4], sr_[4];
    float p_[4];
#pragma unroll
    for (int r = 0; r < 4; ++r) {
        int erow = 16 * w + 4 * g4 + r;
        d_[r] = s_dst[erow]; sr_[r] = s_src[erow]; p_[r] = s_pol[erow];
    }
    float c2v[16], lbv[16];
#pragma unroll
    for (int nt = 0; nt < 16; ++nt) {
        c2v[nt] = c2[nt * 16 + nl];
        lbv[nt] = leb[nt * 16 + nl];
    }
#pragma unroll
    for (int r = 0; r < 4; ++r) {
        const unsigned short* xs = xb + (size_t)sr_[r] * 256 + nl;
#pragma unroll
        for (int nt = 0; nt < 16; ++nt) {
            float m = fmaf(p_[r], acc[nt][r] + c2v[nt], lbv[nt]) + bf2f(xs[nt * 16]);
            acc[nt][r] = fmaxf(m, 0.0f);
        }
    }

    // ---- segmented reduce: in-lane suffix over r (4 consecutive edges) ----
#pragma unroll
    for (int r = 2; r >= 0; --r) {
        bool mm = (d_[r] == d_[r + 1]);
#pragma unroll
        for (int nt = 0; nt < 16; ++nt)
            if (mm) acc[nt][r] += acc[nt][r + 1];
    }
    // cross-group (16-lane quads) continuation: E = run-sum beyond my quad
    int d0n   = __shfl_down(d_[0], 16);
    int fulln = __shfl_down((int)(d_[0] == d_[3]), 16);
    bool cont = (g4 < 3) && (d_[3] == d0n);
    float Cn[16], Ev[16];
#pragma unroll
    for (int nt = 0; nt < 16; ++nt) {
        Cn[nt] = __shfl_down(acc[nt][0], 16);
        Ev[nt] = 0.0f;
    }
    for (int it = 0; it < 3; ++it) {
#pragma unroll
        for (int nt = 0; nt < 16; ++nt) {
            float En = __shfl_down(Ev[nt], 16);
            Ev[nt] = cont ? (Cn[nt] + (fulln ? En : 0.0f)) : 0.0f;
        }
    }
#pragma unroll
    for (int r = 0; r < 4; ++r) {
        bool tail = (d_[r] == d_[3]);
#pragma unroll
        for (int nt = 0; nt < 16; ++nt)
            if (tail) acc[nt][r] += Ev[nt];
    }
    // leaders write
    int dpl = __shfl_up(d_[3], 16);
    bool lead0 = (g4 == 0) || (d_[0] != dpl);
#pragma unroll
    for (int r = 0; r < 4; ++r) {
        bool ld = (r == 0) ? lead0 : (d_[r] != d_[r - 1]);
        if (ld) {
            float* ap = aggr + (size_t)d_[r] * 256 + nl;
#pragma unroll
            for (int nt = 0; nt < 16; ++nt)
                unsafeAtomicAdd(ap + nt * 16, acc[nt][r]);
        }
    }
}

// ---------------------------------------------------------------------------
// node1: h = x + aggr -> bf16 -> MFMA @ w1t -> +b1 -> LN -> *g+b -> relu
//        -> bf16 -> hb (global). 64 rows/block, 4 waves.
// ---------------------------------------------------------------------------
__global__ __launch_bounds__(THREADS, 2) void node1_kernel(
    const float* __restrict__ x, const float* __restrict__ aggr,
    const unsigned short* __restrict__ w1t, const float* __restrict__ b1,
    const float* __restrict__ lng, const float* __restrict__ lnb,
    unsigned short* __restrict__ hb, int N)
{
    __shared__ uint4 s_h[64 * 32];   // 64 rows x 512B bf16, granule ^= row&15

    const int tid = threadIdx.x;
    const int nb = blockIdx.x * 64;
    const int el = tid & 63;
    const int c  = tid >> 6;

    // phase A: h = x + aggr -> bf16 swizzled LDS (thread: row el, dims 64c..)
    {
        int row = nb + el; if (row >= N) row = N - 1;
        const float4* xp = (const float4*)(x + (size_t)row * 256 + c * 64);
        const float4* ap = (const float4*)(aggr + (size_t)row * 256 + c * 64);
#pragma unroll
        for (int q = 0; q < 8; ++q) {
            float4 v0 = xp[q*2], v1 = xp[q*2+1];
            float4 a0 = ap[q*2], a1 = ap[q*2+1];
            uint4 pk;
            pk.x = pack2(v0.x + a0.x, v0.y + a0.y);
            pk.y = pack2(v0.z + a0.z, v0.w + a0.w);
            pk.z = pack2(v1.x + a1.x, v1.y + a1.y);
            pk.w = pack2(v1.z + a1.z, v1.w + a1.w);
            s_h[el * 32 + ((c * 8 + q) ^ (el & 15))] = pk;
        }
    }
    __syncthreads();

    const int lane = el, w = c;
    const int nl = lane & 15, g4 = lane >> 4;
    const int arow = 16 * w + nl;

    short8 afr[8];
#pragma unroll
    for (int kt = 0; kt < 8; ++kt)
        afr[kt] = *(const short8*)&s_h[arow * 32 + ((kt * 4 + g4) ^ nl)];

    const short8* wb = (const short8*)w1t;   // [n][k]: 32 chunks/row
    f32x4 acc[16];
#pragma unroll
    for (int nt = 0; nt < 16; ++nt) acc[nt] = (f32x4){0.f, 0.f, 0.f, 0.f};
#pragma unroll
    for (int kt = 0; kt < 8; ++kt) {
#pragma unroll
        for (int nt = 0; nt < 16; ++nt) {
            short8 b = wb[(nt * 16 + nl) * 32 + kt * 4 + g4];
            acc[nt] = __builtin_amdgcn_mfma_f32_16x16x32_bf16(afr[kt], b, acc[nt], 0, 0, 0);
        }
    }

    // bias + LN + scale/shift + relu (rows 16w+4g4+r, cols nl+16nt)
    float b1v[16], gv[16], bv[16];
#pragma unroll
    for (int nt = 0; nt < 16; ++nt) {
        b1v[nt] = b1[nt * 16 + nl];
        gv[nt]  = lng[nt * 16 + nl];
        bv[nt]  = lnb[nt * 16 + nl];
    }
    unsigned short* sh = (unsigned short*)s_h;
#pragma unroll
    for (int r = 0; r < 4; ++r) {
        float s = 0.f, s2 = 0.f;
#pragma unroll
        for (int nt = 0; nt < 16; ++nt) {
            float v = acc[nt][r] + b1v[nt];
            acc[nt][r] = v;
            s += v; s2 = fmaf(v, v, s2);
        }
#pragma unroll
        for (int o = 1; o < 16; o <<= 1) {
            s  += __shfl_xor(s, o);
            s2 += __shfl_xor(s2, o);
        }
        float mu = s * (1.0f / 256.0f);
        float var = s2 * (1.0f / 256.0f) - mu * mu;
        float rs = rsqrtf(var + 1e-5f);
        int row = 16 * w + 4 * g4 + r;
#pragma unroll
        for (int nt = 0; nt < 16; ++nt) {
            float v = reluf(fmaf((acc[nt][r] - mu) * rs, gv[nt], bv[nt]));
            int d = nl + 16 * nt;
            // wave-local rows: safe to overwrite (only this wave reads them)
            sh[row * 256 + (((d >> 3) ^ (row & 15)) << 3) + (d & 7)] = f2bf(v);
        }
    }
    __syncthreads();

    // coalesced readout -> hb
    if (nb + el < N) {
        uint4* hp = (uint4*)(hb + (size_t)(nb + el) * 256 + c * 64);
#pragma unroll
        for (int q = 0; q < 8; ++q)
            hp[q] = s_h[el * 32 + ((c * 8 + q) ^ (el & 15))];
    }
}

// ---------------------------------------------------------------------------
// node2: out = hb @ w2t^T + b2 (fp32 out). A-frags straight from global.
// ---------------------------------------------------------------------------
__global__ __launch_bounds__(THREADS, 2) void node2_kernel(
    const unsigned short* __restrict__ hb, const unsigned short* __restrict__ w2t,
    const float* __restrict__ b2, float* __restrict__ out, int N)
{
    __shared__ float s_o[64 * 260];   // fp32 bounce, stride 260

    const int tid = threadIdx.x;
    const int nb = blockIdx.x * 64;
    const int el = tid & 63;
    const int c  = tid >> 6;
    const int lane = el, w = c;
    const int nl = lane & 15, g4 = lane >> 4;

    int arow = nb + 16 * w + nl; if (arow >= N) arow = N - 1;
    const short8* ap = (const short8*)(hb + (size_t)arow * 256);
    short8 afr[8];
#pragma unroll
    for (int kt = 0; kt < 8; ++kt) afr[kt] = ap[kt * 4 + g4];

    const short8* wb = (const short8*)w2t;
    f32x4 acc[16];
#pragma unroll
    for (int nt = 0; nt < 16; ++nt) acc[nt] = (f32x4){0.f, 0.f, 0.f, 0.f};
#pragma unroll
    for (int kt = 0; kt < 8; ++kt) {
#pragma unroll
        for (int nt = 0; nt < 16; ++nt) {
            short8 b = wb[(nt * 16 + nl) * 32 + kt * 4 + g4];
            acc[nt] = __builtin_amdgcn_mfma_f32_16x16x32_bf16(afr[kt], b, acc[nt], 0, 0, 0);
        }
    }

    float b2v[16];
#pragma unroll
    for (int nt = 0; nt < 16; ++nt) b2v[nt] = b2[nt * 16 + nl];
#pragma unroll
    for (int r = 0; r < 4; ++r) {
        int row = 16 * w + 4 * g4 + r;
#pragma unroll
        for (int nt = 0; nt < 16; ++nt)
            s_o[row * 260 + nl + 16 * nt] = acc[nt][r] + b2v[nt];
    }
    __syncthreads();

    if (nb + el < N) {
        float4* op = (float4*)(out + (size_t)(nb + el) * 256 + c * 64);
#pragma unroll
        for (int q = 0; q < 16; ++q)
            op[q] = *(float4*)&s_o[el * 260 + c * 64 + q * 4];
    }
}

extern "C" void kernel_launch(void* const* d_in, const int* in_sizes, int n_in,
                              void* d_out, int out_size, void* d_ws, size_t ws_size,
                              hipStream_t stream) {
    const float* x   = (const float*)d_in[0];
    const int*   ei  = (const int*)d_in[1];
    const float* ea  = (const float*)d_in[2];
    const float* ew1 = (const float*)d_in[3];
    const float* eb1 = (const float*)d_in[4];
    const float* ew2 = (const float*)d_in[5];
    const float* eb2 = (const float*)d_in[6];
    const float* lew = (const float*)d_in[7];
    const float* leb = (const float*)d_in[8];
    const float* w1  = (const float*)d_in[9];
    const float* b1  = (const float*)d_in[10];
    const float* lng = (const float*)d_in[11];
    const float* lnb = (const float*)d_in[12];
    const float* w2  = (const float*)d_in[13];
    const float* b2  = (const float*)d_in[14];
    float* out = (float*)d_out;

    const int N = in_sizes[0] / 256;
    const int E = in_sizes[1] / 2;

    float* aggr = (float*)d_ws;                           // N*256 f32
    char* p = (char*)(aggr + (size_t)N * 256);
    int* perm = (int*)p;                p += sizeof(int) * (size_t)E;
    int* counts = (int*)p;              p += sizeof(int) * (size_t)N;
    int* bsum = (int*)p;                p += sizeof(int) * 64;
    unsigned short* w23t = (unsigned short*)p;  p += 2 * 256 * 128;
    float* c2 = (float*)p;              p += 4 * 256;
    unsigned short* w1t = (unsigned short*)p;   p += 2 * 256 * 256;
    unsigned short* w2t = (unsigned short*)p;   p += 2 * 256 * 256;
    unsigned short* xb = (unsigned short*)p;    // N*256 bf16
    unsigned short* hb = xb;  // alias: xb consumed by edge before node1 writes

    hipMemsetAsync(aggr, 0, (size_t)N * 256 * sizeof(float), stream);
    hipMemsetAsync(counts, 0, (size_t)N * sizeof(int), stream);

    prep_kernel<<<256, 128, 0, stream>>>(ew2, eb2, lew, w23t, c2);
    prep_wt_kernel<<<512, 256, 0, stream>>>(w1, w2, w1t, w2t);
    xcast_kernel<<<(int)(((size_t)N * 256) / 2048), 256, 0, stream>>>(x, xb);

    hist_kernel<<<(E + 255) / 256, 256, 0, stream>>>(ei, counts, E);
    const int nsb = (N + 1023) / 1024;
    scan_a_kernel<<<nsb, 1024, 0, stream>>>(counts, bsum, N);
    scan_b_kernel<<<1, 64, 0, stream>>>(bsum, nsb);
    scan_c_kernel<<<nsb, 1024, 0, stream>>>(counts, bsum, N);
    scatter_kernel<<<(E + 255) / 256, 256, 0, stream>>>(ei, counts, perm, E);

    edge_mfma_kernel<<<E / ET, THREADS, 0, stream>>>(
        xb, ei, ea, ew1, eb1, w23t, c2, leb, perm, aggr, E);

    const int gb = (N + 63) / 64;
    node1_kernel<<<gb, THREADS, 0, stream>>>(x, aggr, w1t, b1, lng, lnb, hb, N);
    node2_kernel<<<gb, THREADS, 0, stream>>>(hb, w2t, b2, out, N);
}

// Round 7
// 671.760 us; speedup vs baseline: 1.8645x; 1.3361x over previous
//
#include <hip/hip_runtime.h>
#include <cstdint>
#include <cstddef>

#define ET 128
#define ETHREADS 512

typedef __attribute__((ext_vector_type(8))) short short8;
typedef __attribute__((ext_vector_type(4))) float f32x4;

__device__ __forceinline__ float reluf(float v) { return fmaxf(v, 0.0f); }

__device__ __forceinline__ unsigned short f2bf(float f) {
    union { float f; unsigned u; } v; v.f = f;
    unsigned r = v.u + 0x7fff + ((v.u >> 16) & 1);   // RNE
    return (unsigned short)(r >> 16);
}
__device__ __forceinline__ unsigned pack2(float a, float b) {
    return (unsigned)f2bf(a) | ((unsigned)f2bf(b) << 16);
}
__device__ __forceinline__ float bf2f(unsigned short u) {
    return __uint_as_float((unsigned)u << 16);
}
__device__ __forceinline__ short8 mk8(unsigned a, unsigned b, unsigned c, unsigned d) {
    union { uint4 u; short8 s; } v; v.u = (uint4){a, b, c, d}; return v.s;
}
__device__ __forceinline__ void gload_lds16(const void* g, void* l) {
    __builtin_amdgcn_global_load_lds(
        (const __attribute__((address_space(1))) unsigned int*)g,
        (__attribute__((address_space(3))) unsigned int*)l, 16, 0, 0);
}

// ---------------------------------------------------------------------------
// Prep: W23T[n][k] = sum_j ew2[k][j]*lew[j][n]  (bf16), c2[n] = eb2 @ lew
// ---------------------------------------------------------------------------
__global__ __launch_bounds__(128) void prep_kernel(
    const float* __restrict__ ew2, const float* __restrict__ eb2,
    const float* __restrict__ lew, unsigned short* __restrict__ w23t,
    float* __restrict__ c2)
{
    __shared__ float s_part[128];
    const int n = blockIdx.x;     // 0..255
    const int k = threadIdx.x;    // 0..127
    float acc = 0.0f;
#pragma unroll 4
    for (int j = 0; j < 128; ++j)
        acc = fmaf(ew2[k * 128 + j], lew[j * 256 + n], acc);
    w23t[n * 128 + k] = f2bf(acc);
    s_part[k] = eb2[k] * lew[k * 256 + n];
    __syncthreads();
    if (k == 0) {
        float s = 0.0f;
        for (int j = 0; j < 128; ++j) s += s_part[j];
        c2[n] = s;
    }
}

// w1t[n][k] = bf16(w1[k][n]); w2t likewise. 512 blocks x 256 threads.
__global__ __launch_bounds__(256) void prep_wt_kernel(
    const float* __restrict__ w1, const float* __restrict__ w2,
    unsigned short* __restrict__ w1t, unsigned short* __restrict__ w2t)
{
    const int bi = blockIdx.x;
    const float* src = (bi < 256) ? w1 : w2;
    unsigned short* dst = (bi < 256) ? w1t : w2t;
    const int k = bi & 255;
    const int n = threadIdx.x;
    dst[n * 256 + k] = f2bf(src[k * 256 + n]);
}

// xb = bf16(x), 8 elems/thread
__global__ __launch_bounds__(256) void xcast_kernel(
    const float* __restrict__ x, unsigned short* __restrict__ xb)
{
    const size_t i = ((size_t)blockIdx.x * 256 + threadIdx.x) * 8;
    float4 v0 = *(const float4*)(x + i);
    float4 v1 = *(const float4*)(x + i + 4);
    uint4 pk;
    pk.x = pack2(v0.x, v0.y); pk.y = pack2(v0.z, v0.w);
    pk.z = pack2(v1.x, v1.y); pk.w = pack2(v1.z, v1.w);
    *(uint4*)(xb + i) = pk;
}

// ---------------------------------------------------------------------------
// Counting sort of edges by dst: hist -> 3-phase scan -> scatter(perm)
// ---------------------------------------------------------------------------
__global__ __launch_bounds__(256) void hist_kernel(
    const int* __restrict__ ei, int* __restrict__ counts, int E)
{
    int e = blockIdx.x * 256 + threadIdx.x;
    if (e < E) atomicAdd(&counts[ei[(long long)E + e]], 1);
}

__global__ __launch_bounds__(1024) void scan_a_kernel(
    int* __restrict__ counts, int* __restrict__ bsum, int N)
{
    __shared__ int wsum[16];
    const int tid = threadIdx.x;
    const int lane = tid & 63, wid = tid >> 6;
    const int idx = blockIdx.x * 1024 + tid;
    int v = (idx < N) ? counts[idx] : 0;
    int incl = v;
#pragma unroll
    for (int off = 1; off < 64; off <<= 1) {
        int t = __shfl_up(incl, off);
        if (lane >= off) incl += t;
    }
    if (lane == 63) wsum[wid] = incl;
    __syncthreads();
    int wpre = 0, tot = 0;
#pragma unroll
    for (int w = 0; w < 16; ++w) {
        int s = wsum[w];
        tot += s;
        if (w < wid) wpre += s;
    }
    if (idx < N) counts[idx] = wpre + incl - v;   // block-local exclusive
    if (tid == 0) bsum[blockIdx.x] = tot;
}

__global__ __launch_bounds__(64) void scan_b_kernel(int* __restrict__ bsum, int nb)
{
    const int lane = threadIdx.x;
    int v = (lane < nb) ? bsum[lane] : 0;
    int incl = v;
#pragma unroll
    for (int off = 1; off < 64; off <<= 1) {
        int t = __shfl_up(incl, off);
        if (lane >= off) incl += t;
    }
    if (lane < nb) bsum[lane] = incl - v;   // exclusive
}

__global__ __launch_bounds__(1024) void scan_c_kernel(
    int* __restrict__ counts, const int* __restrict__ bsum, int N)
{
    const int idx = blockIdx.x * 1024 + threadIdx.x;
    if (idx < N) counts[idx] += bsum[blockIdx.x];
}

__global__ __launch_bounds__(256) void scatter_kernel(
    const int* __restrict__ ei, int* __restrict__ cursor,
    int* __restrict__ perm, int E)
{
    int e = blockIdx.x * 256 + threadIdx.x;
    if (e < E) {
        int d = ei[(long long)E + e];
        int pos = atomicAdd(&cursor[d], 1);
        perm[pos] = e;
    }
}

// ---------------------------------------------------------------------------
// Edge pipeline (dst-sorted, MFMA). Block = 128 edges, 8 waves (512 thr).
// W23T staged per block in two 32KB column-halves via global_load_lds
// (linear dest, XOR-swizzled SOURCE index); x gathered bf16 in epilogue.
// LDS ~76KB -> 2 blocks/CU -> 16 waves/CU.
// ---------------------------------------------------------------------------
__global__ __launch_bounds__(ETHREADS, 4) void edge_mfma_kernel(
    const unsigned short* __restrict__ xb, const int* __restrict__ ei,
    const float* __restrict__ ea,
    const float* __restrict__ ew1, const float* __restrict__ eb1,
    const unsigned short* __restrict__ w23t, const float* __restrict__ c2,
    const float* __restrict__ leb, const int* __restrict__ perm,
    float* __restrict__ aggr, int E)
{
    __shared__ float s_attr[ET * 17];   //  8704 B
    __shared__ uint4 s_hid4[ET * 16];   // 32768 B, granule ^= row&15
    __shared__ uint4 s_w[2048];         // 32768 B, one column-half of W23T
    __shared__ int   s_pe[ET];
    __shared__ int   s_src[ET];
    __shared__ int   s_dst[ET];
    __shared__ float s_pol[ET];

    const int tid = threadIdx.x;
    const long long eb0 = (long long)blockIdx.x * ET;

    if (tid < ET) {
        int e = perm[eb0 + tid];
        s_pe[tid]  = e;
        s_src[tid] = ei[e];
        s_dst[tid] = ei[(long long)E + e];
    }
    // stage W23T half 0 (cols n=0..127, 32KB) -> s_w
    {
        int j = tid;
#pragma unroll
        for (int rnd = 0; rnd < 4; ++rnd, j += ETHREADS) {
            int fj = j ^ ((j >> 4) & 7);
            gload_lds16(w23t + (size_t)fj * 8, &s_w[j]);
        }
    }
    __syncthreads();
    for (int i = tid; i < ET * 17; i += ETHREADS) {
        int idx = i / 17;
        int k = i - idx * 17;
        s_attr[i] = ea[(size_t)s_pe[idx] * 17 + k];
    }
    __syncthreads();
    if (tid < ET) s_pol[tid] = fminf(fmaxf(s_attr[tid * 17], 0.0f), 1.0f) + 0.01f;

    const int el = tid & (ET - 1);   // edge row for phase 1
    const int c  = tid >> 7;         // dim group 0..3

    // ---- phase 1: hid = relu(raw @ ew1 + eb1); thread does dims 32c..32c+31
    float acc1[32];
#pragma unroll
    for (int j4 = 0; j4 < 8; ++j4) {
        float4 b = *(const float4*)(eb1 + c * 32 + j4 * 4);
        acc1[j4*4+0] = b.x; acc1[j4*4+1] = b.y;
        acc1[j4*4+2] = b.z; acc1[j4*4+3] = b.w;
    }
#pragma unroll
    for (int k = 0; k < 16; ++k) {
        float rk = s_attr[el * 17 + 1 + k];
#pragma unroll
        for (int j4 = 0; j4 < 8; ++j4) {
            float4 wv = *(const float4*)(ew1 + k * 128 + c * 32 + j4 * 4);
            acc1[j4*4+0] = fmaf(rk, wv.x, acc1[j4*4+0]);
            acc1[j4*4+1] = fmaf(rk, wv.y, acc1[j4*4+1]);
            acc1[j4*4+2] = fmaf(rk, wv.z, acc1[j4*4+2]);
            acc1[j4*4+3] = fmaf(rk, wv.w, acc1[j4*4+3]);
        }
    }
    // relu -> bf16 pack -> swizzled LDS write (granule ^= row&15)
#pragma unroll
    for (int q = 0; q < 4; ++q) {
        uint4 pk;
        pk.x = pack2(reluf(acc1[q*8+0]), reluf(acc1[q*8+1]));
        pk.y = pack2(reluf(acc1[q*8+2]), reluf(acc1[q*8+3]));
        pk.z = pack2(reluf(acc1[q*8+4]), reluf(acc1[q*8+5]));
        pk.w = pack2(reluf(acc1[q*8+6]), reluf(acc1[q*8+7]));
        s_hid4[el * 16 + ((4 * c + q) ^ (el & 15))] = pk;
    }
    __syncthreads();   // drains vmcnt: W-half-0 staged; s_hid/s_pol visible

    // ---- MFMA: wave w (0..7) -> edge rows 16w..16w+15, all 256 out dims ----
    const int lane = tid & 63;
    const int w = tid >> 6;
    const int nl = lane & 15, g4 = lane >> 4;

    short8 afr[4];
#pragma unroll
    for (int kt = 0; kt < 4; ++kt)
        afr[kt] = *(const short8*)&s_hid4[(16 * w + nl) * 16 + ((4 * kt + g4) ^ nl)];

    f32x4 acc[16];
#pragma unroll
    for (int nt = 0; nt < 16; ++nt) acc[nt] = (f32x4){0.f, 0.f, 0.f, 0.f};

#pragma unroll
    for (int h = 0; h < 2; ++h) {
        if (h) {
            __syncthreads();   // all waves done reading half 0
            const unsigned short* wh = w23t + 128 * 128;
            int j = tid;
#pragma unroll
            for (int rnd = 0; rnd < 4; ++rnd, j += ETHREADS) {
                int fj = j ^ ((j >> 4) & 7);
                gload_lds16(wh + (size_t)fj * 8, &s_w[j]);
            }
            __syncthreads();   // half 1 staged (barrier drains vmcnt)
        }
#pragma unroll
        for (int kt = 0; kt < 4; ++kt) {
#pragma unroll
            for (int ntl = 0; ntl < 8; ++ntl) {
                int cidx = (((ntl * 16 + nl) * 16 + kt * 4 + g4)) ^ (nl & 7);
                short8 b = *(const short8*)&s_w[cidx];
                acc[h * 8 + ntl] =
                    __builtin_amdgcn_mfma_f32_16x16x32_bf16(afr[kt], b, acc[h * 8 + ntl], 0, 0, 0);
            }
        }
    }

    // ---- epilogue: C-layout row m = 4*g4+r, col n = 16*nt+nl
    int   d_[4], sr_[4];
    float p_[4];
#pragma unroll
    for (int r = 0; r < 4; ++r) {
        int erow = 16 * w + 4 * g4 + r;
        d_[r] = s_dst[erow]; sr_[r] = s_src[erow]; p_[r] = s_pol[erow];
    }
    float c2v[16], lbv[16];
#pragma unroll
    for (int nt = 0; nt < 16; ++nt) {
        c2v[nt] = c2[nt * 16 + nl];
        lbv[nt] = leb[nt * 16 + nl];
    }
#pragma unroll
    for (int r = 0; r < 4; ++r) {
        const unsigned short* xs = xb + (size_t)sr_[r] * 256 + nl;
#pragma unroll
        for (int nt = 0; nt < 16; ++nt) {
            float m = fmaf(p_[r], acc[nt][r] + c2v[nt], lbv[nt]) + bf2f(xs[nt * 16]);
            acc[nt][r] = fmaxf(m, 0.0f);
        }
    }

    // ---- segmented reduce: in-lane suffix over r (4 consecutive edges) ----
#pragma unroll
    for (int r = 2; r >= 0; --r) {
        bool mm = (d_[r] == d_[r + 1]);
#pragma unroll
        for (int nt = 0; nt < 16; ++nt)
            if (mm) acc[nt][r] += acc[nt][r + 1];
    }
    // cross-group (16-lane quads) continuation within the wave
    int d0n   = __shfl_down(d_[0], 16);
    int fulln = __shfl_down((int)(d_[0] == d_[3]), 16);
    bool cont = (g4 < 3) && (d_[3] == d0n);
    float Cn[16], Ev[16];
#pragma unroll
    for (int nt = 0; nt < 16; ++nt) {
        Cn[nt] = __shfl_down(acc[nt][0], 16);
        Ev[nt] = 0.0f;
    }
    for (int it = 0; it < 3; ++it) {
#pragma unroll
        for (int nt = 0; nt < 16; ++nt) {
            float En = __shfl_down(Ev[nt], 16);
            Ev[nt] = cont ? (Cn[nt] + (fulln ? En : 0.0f)) : 0.0f;
        }
    }
#pragma unroll
    for (int r = 0; r < 4; ++r) {
        bool tail = (d_[r] == d_[3]);
#pragma unroll
        for (int nt = 0; nt < 16; ++nt)
            if (tail) acc[nt][r] += Ev[nt];
    }
    // leaders write
    int dpl = __shfl_up(d_[3], 16);
    bool lead0 = (g4 == 0) || (d_[0] != dpl);
#pragma unroll
    for (int r = 0; r < 4; ++r) {
        bool ld = (r == 0) ? lead0 : (d_[r] != d_[r - 1]);
        if (ld) {
            float* ap = aggr + (size_t)d_[r] * 256 + nl;
#pragma unroll
            for (int nt = 0; nt < 16; ++nt)
                unsafeAtomicAdd(ap + nt * 16, acc[nt][r]);
        }
    }
}

// ---------------------------------------------------------------------------
// node1: h = x+aggr (regs, bf16) -> MFMA @ w1t (B in 4x32KB LDS chunks)
//        -> +b1 -> LN -> *g+b -> relu -> bf16 -> hb. 64 rows, 4 waves.
// LDS = 32KB -> 4 blocks/CU.
// ---------------------------------------------------------------------------
__global__ __launch_bounds__(256, 4) void node1_kernel(
    const float* __restrict__ x, const float* __restrict__ aggr,
    const unsigned short* __restrict__ w1t, const float* __restrict__ b1,
    const float* __restrict__ lng, const float* __restrict__ lnb,
    unsigned short* __restrict__ hb, int N)
{
    __shared__ uint4 s_w[2048];   // 32KB: B chunk, then output bounce

    const int tid = threadIdx.x;
    const int nb = blockIdx.x * 64;
    const int lane = tid & 63, w = tid >> 6;
    const int nl = lane & 15, g4 = lane >> 4;

    int arow = nb + 16 * w + nl; if (arow >= N) arow = N - 1;
    const float* xp = x + (size_t)arow * 256;
    const float* ap = aggr + (size_t)arow * 256;

    f32x4 acc[16];
#pragma unroll
    for (int nt = 0; nt < 16; ++nt) acc[nt] = (f32x4){0.f, 0.f, 0.f, 0.f};

#pragma unroll
    for (int q = 0; q < 4; ++q) {
        if (q) __syncthreads();          // prev chunk reads done
        // stage chunk q of w1t: k-granules [8q,8q+8) of every row n
        {
            int j = tid;
#pragma unroll
            for (int rnd = 0; rnd < 8; ++rnd, j += 256) {
                int n = j >> 3, t = j & 7;
                int gg = n * 32 + q * 8 + (t ^ (n & 7));
                gload_lds16(w1t + (size_t)gg * 8, &s_w[j]);
            }
        }
        // A-frags for kt = 2q, 2q+1 (overlaps with staging)
        short8 afr[2];
#pragma unroll
        for (int kk = 0; kk < 2; ++kk) {
            int k0 = (2 * q + kk) * 32 + g4 * 8;
            float4 xv0 = *(const float4*)(xp + k0);
            float4 xv1 = *(const float4*)(xp + k0 + 4);
            float4 av0 = *(const float4*)(ap + k0);
            float4 av1 = *(const float4*)(ap + k0 + 4);
            afr[kk] = mk8(pack2(xv0.x + av0.x, xv0.y + av0.y),
                          pack2(xv0.z + av0.z, xv0.w + av0.w),
                          pack2(xv1.x + av1.x, xv1.y + av1.y),
                          pack2(xv1.z + av1.z, xv1.w + av1.w));
        }
        __syncthreads();                 // drains vmcnt -> chunk staged
#pragma unroll
        for (int kk = 0; kk < 2; ++kk) {
#pragma unroll
            for (int nt = 0; nt < 16; ++nt) {
                int n = nt * 16 + nl;
                short8 b = *(const short8*)&s_w[n * 8 + ((kk * 4 + g4) ^ (n & 7))];
                acc[nt] = __builtin_amdgcn_mfma_f32_16x16x32_bf16(afr[kk], b, acc[nt], 0, 0, 0);
            }
        }
    }

    // bias + LN + scale/shift + relu (rows 16w+4g4+r, cols nl+16nt)
    float b1v[16], gv[16], bv[16];
#pragma unroll
    for (int nt = 0; nt < 16; ++nt) {
        b1v[nt] = b1[nt * 16 + nl];
        gv[nt]  = lng[nt * 16 + nl];
        bv[nt]  = lnb[nt * 16 + nl];
    }
    __syncthreads();   // all MFMA reads of s_w done -> reuse as bounce
    unsigned short* sh = (unsigned short*)s_w;
#pragma unroll
    for (int r = 0; r < 4; ++r) {
        float s = 0.f, s2 = 0.f;
#pragma unroll
        for (int nt = 0; nt < 16; ++nt) {
            float v = acc[nt][r] + b1v[nt];
            acc[nt][r] = v;
            s += v; s2 = fmaf(v, v, s2);
        }
#pragma unroll
        for (int o = 1; o < 16; o <<= 1) {
            s  += __shfl_xor(s, o);
            s2 += __shfl_xor(s2, o);
        }
        float mu = s * (1.0f / 256.0f);
        float var = s2 * (1.0f / 256.0f) - mu * mu;
        float rs = rsqrtf(var + 1e-5f);
        int row = 16 * w + 4 * g4 + r;
#pragma unroll
        for (int nt = 0; nt < 16; ++nt) {
            float v = reluf(fmaf((acc[nt][r] - mu) * rs, gv[nt], bv[nt]));
            int d = nl + 16 * nt;
            sh[row * 256 + (((d >> 3) ^ (row & 15)) << 3) + (d & 7)] = f2bf(v);
        }
    }
    __syncthreads();

    // coalesced readout -> hb
    const int el = tid & 63, cc = tid >> 6;
    if (nb + el < N) {
        uint4* hp = (uint4*)(hb + (size_t)(nb + el) * 256 + cc * 64);
#pragma unroll
        for (int q = 0; q < 8; ++q)
            hp[q] = s_w[el * 32 + ((cc * 8 + q) ^ (el & 15))];
    }
}

// ---------------------------------------------------------------------------
// node2: out = hb @ w2t^T + b2 (fp32). B in 4x32KB LDS chunks; A from global.
// LDS = 32KB -> 4 blocks/CU. Direct scalar stores (16-lane = 64B lines).
// ---------------------------------------------------------------------------
__global__ __launch_bounds__(256, 4) void node2_kernel(
    const unsigned short* __restrict__ hb, const unsigned short* __restrict__ w2t,
    const float* __restrict__ b2, float* __restrict__ out, int N)
{
    __shared__ uint4 s_w[2048];

    const int tid = threadIdx.x;
    const int nb = blockIdx.x * 64;
    const int lane = tid & 63, w = tid >> 6;
    const int nl = lane & 15, g4 = lane >> 4;

    int arow = nb + 16 * w + nl; if (arow >= N) arow = N - 1;
    const short8* ap = (const short8*)(hb + (size_t)arow * 256);
    short8 afr[8];
#pragma unroll
    for (int kt = 0; kt < 8; ++kt) afr[kt] = ap[kt * 4 + g4];

    f32x4 acc[16];
#pragma unroll
    for (int nt = 0; nt < 16; ++nt) acc[nt] = (f32x4){0.f, 0.f, 0.f, 0.f};

#pragma unroll
    for (int q = 0; q < 4; ++q) {
        if (q) __syncthreads();
        {
            int j = tid;
#pragma unroll
            for (int rnd = 0; rnd < 8; ++rnd, j += 256) {
                int n = j >> 3, t = j & 7;
                int gg = n * 32 + q * 8 + (t ^ (n & 7));
                gload_lds16(w2t + (size_t)gg * 8, &s_w[j]);
            }
        }
        __syncthreads();
#pragma unroll
        for (int kk = 0; kk < 2; ++kk) {
#pragma unroll
            for (int nt = 0; nt < 16; ++nt) {
                int n = nt * 16 + nl;
                short8 b = *(const short8*)&s_w[n * 8 + ((kk * 4 + g4) ^ (n & 7))];
                acc[nt] = __builtin_amdgcn_mfma_f32_16x16x32_bf16(afr[2 * q + kk], b, acc[nt], 0, 0, 0);
            }
        }
    }

    float b2v[16];
#pragma unroll
    for (int nt = 0; nt < 16; ++nt) b2v[nt] = b2[nt * 16 + nl];
#pragma unroll
    for (int r = 0; r < 4; ++r) {
        int row = nb + 16 * w + 4 * g4 + r;
        if (row < N) {
            float* op = out + (size_t)row * 256 + nl;
#pragma unroll
            for (int nt = 0; nt < 16; ++nt)
                op[nt * 16] = acc[nt][r] + b2v[nt];
        }
    }
}

extern "C" void kernel_launch(void* const* d_in, const int* in_sizes, int n_in,
                              void* d_out, int out_size, void* d_ws, size_t ws_size,
                              hipStream_t stream) {
    const float* x   = (const float*)d_in[0];
    const int*   ei  = (const int*)d_in[1];
    const float* ea  = (const float*)d_in[2];
    const float* ew1 = (const float*)d_in[3];
    const float* eb1 = (const float*)d_in[4];
    const float* ew2 = (const float*)d_in[5];
    const float* eb2 = (const float*)d_in[6];
    const float* lew = (const float*)d_in[7];
    const float* leb = (const float*)d_in[8];
    const float* w1  = (const float*)d_in[9];
    const float* b1  = (const float*)d_in[10];
    const float* lng = (const float*)d_in[11];
    const float* lnb = (const float*)d_in[12];
    const float* w2  = (const float*)d_in[13];
    const float* b2  = (const float*)d_in[14];
    float* out = (float*)d_out;

    const int N = in_sizes[0] / 256;
    const int E = in_sizes[1] / 2;

    float* aggr = (float*)d_ws;                           // N*256 f32
    char* p = (char*)(aggr + (size_t)N * 256);
    int* perm = (int*)p;                p += sizeof(int) * (size_t)E;
    int* counts = (int*)p;              p += sizeof(int) * (size_t)N;
    int* bsum = (int*)p;                p += sizeof(int) * 64;
    unsigned short* w23t = (unsigned short*)p;  p += 2 * 256 * 128;
    float* c2 = (float*)p;              p += 4 * 256;
    unsigned short* w1t = (unsigned short*)p;   p += 2 * 256 * 256;
    unsigned short* w2t = (unsigned short*)p;   p += 2 * 256 * 256;
    unsigned short* xb = (unsigned short*)p;    // N*256 bf16
    unsigned short* hb = xb;  // alias: xb consumed by edge before node1 writes

    hipMemsetAsync(aggr, 0, (size_t)N * 256 * sizeof(float), stream);
    hipMemsetAsync(counts, 0, (size_t)N * sizeof(int), stream);

    prep_kernel<<<256, 128, 0, stream>>>(ew2, eb2, lew, w23t, c2);
    prep_wt_kernel<<<512, 256, 0, stream>>>(w1, w2, w1t, w2t);
    xcast_kernel<<<(int)(((size_t)N * 256) / 2048), 256, 0, stream>>>(x, xb);

    hist_kernel<<<(E + 255) / 256, 256, 0, stream>>>(ei, counts, E);
    const int nsb = (N + 1023) / 1024;
    scan_a_kernel<<<nsb, 1024, 0, stream>>>(counts, bsum, N);
    scan_b_kernel<<<1, 64, 0, stream>>>(bsum, nsb);
    scan_c_kernel<<<nsb, 1024, 0, stream>>>(counts, bsum, N);
    scatter_kernel<<<(E + 255) / 256, 256, 0, stream>>>(ei, counts, perm, E);

    edge_mfma_kernel<<<E / ET, ETHREADS, 0, stream>>>(
        xb, ei, ea, ew1, eb1, w23t, c2, leb, perm, aggr, E);

    const int gb = (N + 63) / 64;
    node1_kernel<<<gb, 256, 0, stream>>>(x, aggr, w1t, b1, lng, lnb, hb, N);
    node2_kernel<<<gb, 256, 0, stream>>>(hb, w2t, b2, out, N);
}